// Round 16
// baseline (12848.738 us; speedup 1.0000x reference)
//
#include <hip/hip_runtime.h>
#include <cmath>

#define B 128
#define L 64
#define D 512
#define H 256
#define G4 1024
#define TOTROWS 2080   // 64*65/2
#define NBLK 256
#define GF_PAD 16

typedef float fx4 __attribute__((ext_vector_type(4)));

__device__ __forceinline__ float sigf(float x) { return 1.0f / (1.0f + expf(-x)); }

// ---- coherence-point (L3) stores/loads ----
__device__ __forceinline__ void stg_sc_f32(float* p, float v) {
    asm volatile("global_store_dword %0, %1, off sc0 sc1" :: "v"(p), "v"(v) : "memory");
}
__device__ __forceinline__ void stg_sc_f64(double* p, double v) {
    asm volatile("global_store_dwordx2 %0, %1, off sc0 sc1" :: "v"(p), "v"(v) : "memory");
}
__device__ __forceinline__ void stg_sc_f4(float* p, float4 v) {
    fx4 w = __builtin_bit_cast(fx4, v);
    asm volatile("global_store_dwordx4 %0, %1, off sc0 sc1" :: "v"(p), "v"(w) : "memory");
}
// blocking 64B read: loads + vmcnt inside ONE asm block (registers pinned —
// split issue/wait is UNSAFE: compiler may copy/spill in-flight destinations)
__device__ __forceinline__ void ld4x4_sc(const float* p, fx4& a, fx4& b, fx4& c, fx4& d) {
    asm volatile(
        "global_load_dwordx4 %0, %4, off sc0 sc1\n\t"
        "global_load_dwordx4 %1, %4, off offset:16 sc0 sc1\n\t"
        "global_load_dwordx4 %2, %4, off offset:32 sc0 sc1\n\t"
        "global_load_dwordx4 %3, %4, off offset:48 sc0 sc1\n\t"
        "s_waitcnt vmcnt(0)"
        : "=&v"(a), "=&v"(b), "=&v"(c), "=&v"(d)
        : "v"(p) : "memory");
}
__device__ __forceinline__ bool any_nan(fx4 v) {
    return (v[0] != v[0]) | (v[1] != v[1]) | (v[2] != v[2]) | (v[3] != v[3]);
}

__device__ __forceinline__ void st_flag(int* p, int v) {
    __hip_atomic_store(p, v, __ATOMIC_RELAXED, __HIP_MEMORY_SCOPE_AGENT);
}
__device__ __forceinline__ int ld_flag(const int* p) {
    return __hip_atomic_load(p, __ATOMIC_RELAXED, __HIP_MEMORY_SCOPE_AGENT);
}

// 32-block group barrier + acquire fence. Every wave drains its own inline-asm
// VMEM stores (invisible to the compiler's waitcnt pass) before signaling.
__device__ __forceinline__ void group_barrier(int* gflag, int* ggen, int lid, int phase) {
    asm volatile("s_waitcnt vmcnt(0)" ::: "memory");
    __syncthreads();
    if (threadIdx.x == 0) st_flag(gflag + lid * GF_PAD, phase);
    if (lid == 0) {
        if (threadIdx.x < 32)
            while (ld_flag(gflag + threadIdx.x * GF_PAD) < phase) __builtin_amdgcn_s_sleep(1);
        __syncthreads();
        if (threadIdx.x == 0) st_flag(ggen, phase);
    } else if (threadIdx.x == 0) {
        while (ld_flag(ggen) < phase) __builtin_amdgcn_s_sleep(1);
    }
    __builtin_amdgcn_fence(__ATOMIC_ACQUIRE, "agent");
    __syncthreads();
}

// ---------------- init: uh0 -> units chunk; flags zero; hst poison ----------------
__global__ __launch_bounds__(256) void k_init(const int* __restrict__ ex_in,
                                              const float* __restrict__ uh_in,
                                              float* __restrict__ units,
                                              float* __restrict__ hst,
                                              int* __restrict__ flags) {
    int idx = blockIdx.x * 256 + threadIdx.x;   // over 1,048,576
    if (idx < 8448) flags[idx] = 0;
    {   // poison all 64 h slices
        float qn = __uint_as_float(0x7fc00000u);
        float4 q4; q4.x = qn; q4.y = qn; q4.z = qn; q4.w = qn;
        ((float4*)hst)[idx] = q4;
    }
    int bt = idx >> 7;
    int r  = idx & 127;
    float m = (ex_in[bt] != 0) ? 1.0f : 0.0f;
    const float4* src = (const float4*)uh_in;
    float4 v = src[idx];
    v.x *= m; v.y *= m; v.z *= m; v.w *= m;
    int b = bt >> 6, t = bt & 63;
    float4* dst = (float4*)units;
    dst[((size_t)b * TOTROWS + 2016 + t) * 128 + r] = v;
}

// ---------------- one-time: W_ih transposed to [d][k][1024] ----------------
__global__ __launch_bounds__(256) void k_wprep_ih(const float* __restrict__ wf,
                                                  const float* __restrict__ wb,
                                                  float* __restrict__ wt) {
    int o = blockIdx.x * 256 + threadIdx.x;   // 2*512*1024
    int n = o & 1023;
    int k = (o >> 10) & 511;
    int d = o >> 19;
    const float* W = d ? wb : wf;
    wt[o] = W[n * 512 + k];
}

// ---------------- one-time: W_hh into per-lane register layout -------------
__global__ __launch_bounds__(256) void k_wprep_hh(const float* __restrict__ wf,
                                                  const float* __restrict__ wb,
                                                  float* __restrict__ wt) {
    int o = blockIdx.x * 256 + threadIdx.x;   // 2*16*256*64
    int c    = o & 3;
    int i4   = (o >> 2) & 3;
    int q    = (o >> 4) & 3;
    int lane = (o >> 6) & 255;
    int jg   = (o >> 14) & 15;
    int d    = o >> 18;
    int jj = lane & 15, kseg = lane >> 4;
    const float* W = d ? wb : wf;
    wt[o] = W[(q * 256 + jg * 16 + jj) * 256 + kseg * 16 + i4 * 4 + c];
}

// ---------------- one-time full xg = uh0 @ W_ih^T (len=64) ----------------
__global__ __launch_bounds__(256) void k_xg(const float* __restrict__ units,
                                            const float* __restrict__ wihT,
                                            float* __restrict__ xg, int len, int offL) {
    __shared__ __align__(16) float As[32 * 132];
    __shared__ __align__(16) float Bs[32 * 132];
    int tid = threadIdx.x;
    int nt = blockIdx.x, mtb = blockIdx.y;
    int d = nt >> 3;
    int gbase = (nt & 7) * 128;
    int M = 128 * len;

    int arow = tid & 127, ahalf = tid >> 7;
    int agm = mtb * 128 + arow;
    const float* aptr = nullptr;
    if (agm < M) {
        int ab = agm / len, at = agm - ab * len;
        aptr = units + ((size_t)ab * TOTROWS + offL + at) * 512;
    }
    int bcol = (tid & 31) * 4, bkr = tid >> 5;
    int tm = tid >> 4, tn = tid & 15;

    float acc[8][8];
#pragma unroll
    for (int i = 0; i < 8; i++)
#pragma unroll
        for (int j = 0; j < 8; j++) acc[i][j] = 0.f;

    for (int k0 = 0; k0 < 512; k0 += 32) {
#pragma unroll
        for (int i4 = 0; i4 < 4; i4++) {
            float4 v;
            if (aptr) v = *(const float4*)&aptr[k0 + ahalf * 16 + i4 * 4];
            else { v.x = v.y = v.z = v.w = 0.f; }
            int kk = ahalf * 16 + i4 * 4;
            As[(kk + 0) * 132 + arow] = v.x;
            As[(kk + 1) * 132 + arow] = v.y;
            As[(kk + 2) * 132 + arow] = v.z;
            As[(kk + 3) * 132 + arow] = v.w;
        }
#pragma unroll
        for (int i = 0; i < 4; i++) {
            int kk = bkr * 4 + i;
            float4 v = *(const float4*)&wihT[((size_t)(d * 512 + k0 + kk)) * 1024 + gbase + bcol];
            *(float4*)&Bs[kk * 132 + bcol] = v;
        }
        __syncthreads();
#pragma unroll 4
        for (int k = 0; k < 32; k++) {
            float4 a0 = *(const float4*)&As[k * 132 + tm * 8];
            float4 a1 = *(const float4*)&As[k * 132 + tm * 8 + 4];
            float4 b0 = *(const float4*)&Bs[k * 132 + tn * 8];
            float4 b1 = *(const float4*)&Bs[k * 132 + tn * 8 + 4];
            float av[8] = {a0.x, a0.y, a0.z, a0.w, a1.x, a1.y, a1.z, a1.w};
            float bv[8] = {b0.x, b0.y, b0.z, b0.w, b1.x, b1.y, b1.z, b1.w};
#pragma unroll
            for (int i = 0; i < 8; i++)
#pragma unroll
                for (int j = 0; j < 8; j++) acc[i][j] = fmaf(av[i], bv[j], acc[i][j]);
        }
        __syncthreads();
    }
#pragma unroll
    for (int i = 0; i < 8; i++) {
        int gm = mtb * 128 + tm * 8 + i;
        if (gm < M) {
            int bb = gm / len, tt = gm - bb * len;
            float* Cp = xg + ((size_t)(d * B + bb) * L + tt) * G4 + gbase + tn * 8;
            float4 v0; v0.x = acc[i][0]; v0.y = acc[i][1]; v0.z = acc[i][2]; v0.w = acc[i][3];
            float4 v1; v1.x = acc[i][4]; v1.y = acc[i][5]; v1.z = acc[i][6]; v1.w = acc[i][7];
            *(float4*)&Cp[0] = v0;
            *(float4*)&Cp[4] = v1;
        }
    }
}

// ---------------- persistent: NaN-poison dataflow, 1 sync/step ----
// block = (jg = bid&15, sg = (bid>>4)&7, d = bid>>7). Group = sg (32 blocks).
// hs region per kseg is quarter-wave-private: stage thread (bS,kc) and dot
// thread (jj,kseg=kc) are the SAME 16 lanes -> no stage->dot __syncthreads.
// pb double-buffered by step parity -> no trailing __syncthreads.
__global__ __launch_bounds__(256, 1) void k_persist(
        float* __restrict__ xg, const float* __restrict__ wtHH,
        const float* __restrict__ bias_f, const float* __restrict__ bias_b,
        const float* __restrict__ ow, const float* __restrict__ h0,
        const float* __restrict__ c0, float* __restrict__ hst,
        double* __restrict__ o_part, const float* __restrict__ ob,
        const int* __restrict__ ex_in, float* __restrict__ dec,
        float* __restrict__ units, float* __restrict__ out_or,
        float* __restrict__ out_ex, int* flags) {
    __shared__ __align__(16) float hs[256 * 16];        // 16KB, kseg-region private
    __shared__ __align__(16) float pb[2][4 * 16 * 68];  // 2 x 17.4KB (wave slices)
    __shared__ float osh[68];
    __shared__ float dsh[64];
    __shared__ float exl[64];
    int tid = threadIdx.x;
    int bid = blockIdx.x;
    int jg = bid & 15, sg = (bid >> 4) & 7, d = bid >> 7;
    int lid = jg + 16 * d;
    int b0 = sg * 16, j0 = jg * 16;
    const size_t HB = (size_t)2 * B * H;             // per-step h stride

    int* gflag = flags + sg * 32 * GF_PAD;
    int* ggen  = flags + 4096 + sg * GF_PAD;
    int gph = 0;

    // W_hh slice resident in registers for the whole kernel
    float4 wreg[16];
    {
        const float4* wp = (const float4*)(wtHH + ((size_t)(d * 16 + jg) * 256 + tid) * 64);
#pragma unroll
        for (int m = 0; m < 16; m++) wreg[m] = wp[m];
    }
    int bF = tid >> 4, jjF = tid & 15;
    int bG = b0 + bF, jG = j0 + jjF;
    const float* biasp = d ? bias_b : bias_f;
    float bias4[4] = { biasp[jG], biasp[256 + jG], biasp[512 + jG], biasp[768 + jG] };
    float owv = ow[d * H + jG];
    float c0v = c0[d * H + jG];
    int bS = tid & 15, kc = tid >> 4;
    int swz = (((bS >> 2) ^ (kc & 3)) << 2) + (bS & 3);
    float4 h0s[4];
#pragma unroll
    for (int i4 = 0; i4 < 4; i4++)
        h0s[i4] = *(const float4*)&h0[d * H + kc * 16 + i4 * 4];
    const float* hstb = hst + ((size_t)(d * B + b0 + bS)) * H + kc * 16;
    float*       hwr  = hst + ((size_t)(d * B + bG)) * H + jG;
    float c_reg = 0.f;
    if (d == 0 && tid < 64) exl[tid] = (ex_in[(b0 + jg) * 64 + tid] != 0) ? 1.0f : 0.0f;

    for (int it = 0; it < 64; ++it) {
        int len = 64 - it;
        int offL = len * (len - 1) / 2;
        int n = len - 1;

        // ---- timestep chain: stage (quarter-wave local) | dot | sync | finalize ----
        for (int s = 0; s < len; ++s) {
            int t = d ? (n - s) : s;
            size_t xgo = (((size_t)(d * B + bG)) * L + t) * G4 + jG;
            float x0 = xg[xgo], x1 = xg[xgo + 256], x2 = xg[xgo + 512], x3 = xg[xgo + 768];
            if (s == 0) {
#pragma unroll
                for (int i4 = 0; i4 < 4; i4++) {
                    int kk = kc * 16 + i4 * 4;
                    hs[(kk + 0) * 16 + swz] = h0s[i4].x;
                    hs[(kk + 1) * 16 + swz] = h0s[i4].y;
                    hs[(kk + 2) * 16 + swz] = h0s[i4].z;
                    hs[(kk + 3) * 16 + swz] = h0s[i4].w;
                }
            } else {
                const float* hp = hstb + (size_t)(s - 1) * HB;
                fx4 v0, v1, v2, v3;
                ld4x4_sc(hp, v0, v1, v2, v3);
                while (any_nan(v0) | any_nan(v1) | any_nan(v2) | any_nan(v3)) {
                    __builtin_amdgcn_s_sleep(2);
                    ld4x4_sc(hp, v0, v1, v2, v3);
                }
                float arr[16] = { v0[0], v0[1], v0[2], v0[3], v1[0], v1[1], v1[2], v1[3],
                                  v2[0], v2[1], v2[2], v2[3], v3[0], v3[1], v3[2], v3[3] };
#pragma unroll
                for (int i = 0; i < 16; i++)
                    hs[(kc * 16 + i) * 16 + swz] = arr[i];
            }
            // NO __syncthreads: stage->dot dependency is within the same 16 lanes
            float* pbc = pb[s & 1];
            {   // dot
                int jj = tid & 15, kseg = tid >> 4;
                int ks3 = kseg & 3;
                float acc[4][16];
#pragma unroll
                for (int q = 0; q < 4; q++)
#pragma unroll
                    for (int u = 0; u < 16; u++) acc[q][u] = 0.f;
#pragma unroll
                for (int i4 = 0; i4 < 4; i4++) {
#pragma unroll
                    for (int c = 0; c < 4; c++) {
                        int k = (kseg << 4) + (i4 << 2) + c;
                        const float* hb = &hs[k << 4];
                        float4 hv[4];
#pragma unroll
                        for (int bq = 0; bq < 4; bq++)
                            hv[bq] = *(const float4*)&hb[((bq ^ ks3) << 2)];
#pragma unroll
                        for (int q = 0; q < 4; q++) {
                            float4 wv = wreg[q * 4 + i4];
                            float w = (c == 0) ? wv.x : (c == 1) ? wv.y : (c == 2) ? wv.z : wv.w;
#pragma unroll
                            for (int bq = 0; bq < 4; bq++) {
                                acc[q][bq * 4 + 0] = fmaf(hv[bq].x, w, acc[q][bq * 4 + 0]);
                                acc[q][bq * 4 + 1] = fmaf(hv[bq].y, w, acc[q][bq * 4 + 1]);
                                acc[q][bq * 4 + 2] = fmaf(hv[bq].z, w, acc[q][bq * 4 + 2]);
                                acc[q][bq * 4 + 3] = fmaf(hv[bq].w, w, acc[q][bq * 4 + 3]);
                            }
                        }
                    }
                }
#pragma unroll
                for (int q = 0; q < 4; q++)
#pragma unroll
                    for (int u = 0; u < 16; u++) {
                        acc[q][u] += __shfl_xor(acc[q][u], 16);
                        acc[q][u] += __shfl_xor(acc[q][u], 32);
                    }
                if (!(tid & 48)) {
                    int slice = tid >> 6;
                    float* pbp = &pbc[(slice * 16 + jj) * 68];
#pragma unroll
                    for (int bb = 0; bb < 16; bb++) {
                        float4 v; v.x = acc[0][bb]; v.y = acc[1][bb]; v.z = acc[2][bb]; v.w = acc[3][bb];
                        *(float4*)&pbp[bb * 4] = v;
                    }
                }
            }
            __syncthreads();   // pb slices from all waves
            {   // finalize
                float g4[4] = {0.f, 0.f, 0.f, 0.f};
#pragma unroll
                for (int sl = 0; sl < 4; sl++) {
                    float4 pv = *(const float4*)&pbc[(sl * 16 + jjF) * 68 + bF * 4];
                    g4[0] += pv.x; g4[1] += pv.y; g4[2] += pv.z; g4[3] += pv.w;
                }
                float g0 = x0 + bias4[0] + g4[0];
                float g1 = x1 + bias4[1] + g4[1];
                float g2 = x2 + bias4[2] + g4[2];
                float g3 = x3 + bias4[3] + g4[3];
                float c_old = (s == 0) ? c0v : c_reg;
                float ig = sigf(g0);
                float fg = sigf(g1);
                float gv = tanhf(g2);
                float og = sigf(g3);
                float c = fg * c_old + ig * gv;
                float h = og * tanhf(c);
                c_reg = c;
                stg_sc_f32(hwr + (size_t)s * HB, h);
                double contrib = (double)h * (double)owv;
#pragma unroll
                for (int off = 8; off > 0; off >>= 1) contrib += __shfl_xor(contrib, off, 16);
                if (jjF == 0) stg_sc_f64(&o_part[(((size_t)(d * 16 + jg)) * B + bG) * L + t], contrib);
            }
            // NO trailing __syncthreads: pb is parity double-buffered
        }
        ++gph; group_barrier(gflag, ggen, lid, gph);

        // ---- orient + decisions (d==0 blocks; sample b0+jg each) ----
        if (d == 0) {
            int bo = b0 + jg;
            float oval = 0.f;
            if (tid < len) {
                double sum = (double)ob[0];
#pragma unroll 4
                for (int i = 0; i < 32; i++) sum += o_part[((size_t)i * B + bo) * L + tid];
                oval = (float)sum;
                osh[tid] = oval;
                out_or[(size_t)bo * TOTROWS + offL + tid] = oval;
                out_ex[(size_t)bo * TOTROWS + offL + tid] = exl[tid];
            }
            __syncthreads();
            float newex = 0.f;
            if (tid < n) {
                float lw = (oval > 0.f && exl[tid] != 0.f) ? 1.f : 0.f;
                float rw = (!(osh[tid + 1] > 0.f) && exl[tid + 1] != 0.f) ? 1.f : 0.f;
                stg_sc_f32(dec + bo * 64 + tid, lw + 2.f * rw);
                newex = ((lw + rw) > 0.f) ? 1.f : 0.f;
            }
            __syncthreads();
            if (tid < n) exl[tid] = newex;
        }
        ++gph; group_barrier(gflag, ggen, lid, gph);

        // ---- merge units + xg (group-local assignment) + re-arm h poison ----
        if (len > 1) {
            int bu = b0 + (lid >> 1);
            if (tid < n) dsh[tid] = dec[bu * 64 + tid];
            __syncthreads();
            {   // units: column (bu, k)
                int k = ((lid & 1) << 8) + tid;
                const float* src = units + ((size_t)bu * TOTROWS + offL) * D + k;
                float* dst = units + ((size_t)bu * TOTROWS + (offL - n)) * D + k;
                float cur = src[0];
                int tt = 0;
                while (tt < n) {
                    int m = (n - tt < 8) ? (n - tt) : 8;
                    float nx[8];
#pragma unroll
                    for (int i = 0; i < 8; i++) if (i < m) nx[i] = src[(size_t)(tt + i + 1) * D];
#pragma unroll
                    for (int i = 0; i < 8; i++) if (i < m) {
                        int dv = (int)dsh[tt + i];
                        stg_sc_f32(dst + (size_t)(tt + i) * D,
                                   (float)(dv & 1) * cur + (float)(dv >> 1) * nx[i]);
                        cur = nx[i];
                    }
                    tt += m;
                }
            }
            {   // xg: (d2 = lid&1, sample bu), float4 per thread
                int d2 = lid & 1;
                float* base = xg + ((size_t)(d2 * B + bu) * L) * G4 + tid * 4;
                float4 cur = *(const float4*)base;
                int tt = 0;
                while (tt < n) {
                    int m = (n - tt < 8) ? (n - tt) : 8;
                    float4 nx[8];
#pragma unroll
                    for (int i = 0; i < 8; i++) if (i < m)
                        nx[i] = *(const float4*)(base + (size_t)(tt + i + 1) * G4);
#pragma unroll
                    for (int i = 0; i < 8; i++) if (i < m) {
                        int dv = (int)dsh[tt + i];
                        float flw = (float)(dv & 1), frw = (float)(dv >> 1);
                        float4 o;
                        o.x = flw * cur.x + frw * nx[i].x;
                        o.y = flw * cur.y + frw * nx[i].y;
                        o.z = flw * cur.z + frw * nx[i].z;
                        o.w = flw * cur.w + frw * nx[i].w;
                        stg_sc_f4(base + (size_t)(tt + i) * G4, o);
                        cur = nx[i];
                    }
                    tt += m;
                }
            }
            {   // poison own (b,j) h-tile for next iteration
                float qn = __uint_as_float(0x7fc00000u);
                for (int s2 = 0; s2 < n; ++s2)
                    stg_sc_f32(hwr + (size_t)s2 * HB, qn);
            }
            ++gph; group_barrier(gflag, ggen, lid, gph);
        }
    }
}

extern "C" void kernel_launch(void* const* d_in, const int* in_sizes, int n_in,
                              void* d_out, int out_size, void* d_ws, size_t ws_size,
                              hipStream_t stream) {
    const int*   ex_in   = (const int*)d_in[0];
    const float* uh_in   = (const float*)d_in[1];
    const float* w_ih_f  = (const float*)d_in[2];
    const float* w_hh_f  = (const float*)d_in[3];
    const float* b_f     = (const float*)d_in[4];
    const float* w_ih_b  = (const float*)d_in[5];
    const float* w_hh_b  = (const float*)d_in[6];
    const float* b_b     = (const float*)d_in[7];
    const float* orientw = (const float*)d_in[8];
    const float* orientb = (const float*)d_in[9];
    const float* h0      = (const float*)d_in[10];
    const float* c0      = (const float*)d_in[11];

    float* units  = (float*)d_out;
    float* out_or = units + (size_t)B * TOTROWS * D;
    float* out_ex = out_or + (size_t)B * TOTROWS;

    float* xg    = (float*)d_ws;                       // 16,777,216 f (64MB)
    float* wihT  = xg + (size_t)2 * B * L * G4;        // 1,048,576 f
    float* wtHH  = wihT + (size_t)1048576;             // 524,288 f
    float* hst   = wtHH + (size_t)524288;              // 64 * 2*B*H = 4,194,304 f (16MB)
    float* dec   = hst + (size_t)64 * 2 * B * H;       // 8,192 f
    double* opart = (double*)(dec + B * L);            // 262,144 d (2MB)
    int*   flags = (int*)(opart + 262144);             // 8,448 ints

    k_init<<<4096, 256, 0, stream>>>(ex_in, uh_in, units, hst, flags);
    k_wprep_ih<<<4096, 256, 0, stream>>>(w_ih_f, w_ih_b, wihT);
    k_wprep_hh<<<2048, 256, 0, stream>>>(w_hh_f, w_hh_b, wtHH);
    k_xg<<<dim3(16, 64), 256, 0, stream>>>(units, wihT, xg, 64, 2016);
    k_persist<<<NBLK, 256, 0, stream>>>(xg, wtHH, b_f, b_b, orientw, h0, c0,
                                        hst, opart, orientb, ex_in, dec,
                                        units, out_or, out_ex, flags);
    (void)in_sizes; (void)n_in; (void)out_size; (void)ws_size;
}

// Round 17
// 11238.477 us; speedup vs baseline: 1.1433x; 1.1433x over previous
//
#include <hip/hip_runtime.h>
#include <cmath>

#define B 128
#define L 64
#define D 512
#define H 256
#define G4 1024
#define TOTROWS 2080   // 64*65/2
#define NBLK 256
#define GF_PAD 16

typedef float fx4 __attribute__((ext_vector_type(4)));

__device__ __forceinline__ float sigf(float x) { return 1.0f / (1.0f + expf(-x)); }

// ---- coherence-point (L3) stores/loads ----
__device__ __forceinline__ void stg_sc_f32(float* p, float v) {
    asm volatile("global_store_dword %0, %1, off sc0 sc1" :: "v"(p), "v"(v) : "memory");
}
__device__ __forceinline__ void stg_sc_f64(double* p, double v) {
    asm volatile("global_store_dwordx2 %0, %1, off sc0 sc1" :: "v"(p), "v"(v) : "memory");
}
__device__ __forceinline__ void stg_sc_f4(float* p, float4 v) {
    fx4 w = __builtin_bit_cast(fx4, v);
    asm volatile("global_store_dwordx4 %0, %1, off sc0 sc1" :: "v"(p), "v"(w) : "memory");
}
// blocking 64B read: loads + vmcnt inside ONE asm block (registers pinned —
// split issue/wait is UNSAFE: compiler may copy/spill in-flight destinations)
__device__ __forceinline__ void ld4x4_sc(const float* p, fx4& a, fx4& b, fx4& c, fx4& d) {
    asm volatile(
        "global_load_dwordx4 %0, %4, off sc0 sc1\n\t"
        "global_load_dwordx4 %1, %4, off offset:16 sc0 sc1\n\t"
        "global_load_dwordx4 %2, %4, off offset:32 sc0 sc1\n\t"
        "global_load_dwordx4 %3, %4, off offset:48 sc0 sc1\n\t"
        "s_waitcnt vmcnt(0)"
        : "=&v"(a), "=&v"(b), "=&v"(c), "=&v"(d)
        : "v"(p) : "memory");
}
__device__ __forceinline__ bool any_nan(fx4 v) {
    return (v[0] != v[0]) | (v[1] != v[1]) | (v[2] != v[2]) | (v[3] != v[3]);
}

__device__ __forceinline__ void st_flag(int* p, int v) {
    __hip_atomic_store(p, v, __ATOMIC_RELAXED, __HIP_MEMORY_SCOPE_AGENT);
}
__device__ __forceinline__ int ld_flag(const int* p) {
    return __hip_atomic_load(p, __ATOMIC_RELAXED, __HIP_MEMORY_SCOPE_AGENT);
}

// 32-block group barrier + acquire fence. Every wave drains its own inline-asm
// VMEM stores (invisible to the compiler's waitcnt pass) before signaling.
__device__ __forceinline__ void group_barrier(int* gflag, int* ggen, int lid, int phase) {
    asm volatile("s_waitcnt vmcnt(0)" ::: "memory");
    __syncthreads();
    if (threadIdx.x == 0) st_flag(gflag + lid * GF_PAD, phase);
    if (lid == 0) {
        if (threadIdx.x < 32)
            while (ld_flag(gflag + threadIdx.x * GF_PAD) < phase) __builtin_amdgcn_s_sleep(1);
        __syncthreads();
        if (threadIdx.x == 0) st_flag(ggen, phase);
    } else if (threadIdx.x == 0) {
        while (ld_flag(ggen) < phase) __builtin_amdgcn_s_sleep(1);
    }
    __builtin_amdgcn_fence(__ATOMIC_ACQUIRE, "agent");
    __syncthreads();
}

// ---------------- init: uh0 -> units chunk; flags zero; hst poison ----------------
__global__ __launch_bounds__(256) void k_init(const int* __restrict__ ex_in,
                                              const float* __restrict__ uh_in,
                                              float* __restrict__ units,
                                              float* __restrict__ hst,
                                              int* __restrict__ flags) {
    int idx = blockIdx.x * 256 + threadIdx.x;   // over 1,048,576
    if (idx < 8448) flags[idx] = 0;
    {   // poison all 64 h slices
        float qn = __uint_as_float(0x7fc00000u);
        float4 q4; q4.x = qn; q4.y = qn; q4.z = qn; q4.w = qn;
        ((float4*)hst)[idx] = q4;
    }
    int bt = idx >> 7;
    int r  = idx & 127;
    float m = (ex_in[bt] != 0) ? 1.0f : 0.0f;
    const float4* src = (const float4*)uh_in;
    float4 v = src[idx];
    v.x *= m; v.y *= m; v.z *= m; v.w *= m;
    int b = bt >> 6, t = bt & 63;
    float4* dst = (float4*)units;
    dst[((size_t)b * TOTROWS + 2016 + t) * 128 + r] = v;
}

// ---------------- one-time: W_ih transposed to [d][k][1024] ----------------
__global__ __launch_bounds__(256) void k_wprep_ih(const float* __restrict__ wf,
                                                  const float* __restrict__ wb,
                                                  float* __restrict__ wt) {
    int o = blockIdx.x * 256 + threadIdx.x;   // 2*512*1024
    int n = o & 1023;
    int k = (o >> 10) & 511;
    int d = o >> 19;
    const float* W = d ? wb : wf;
    wt[o] = W[n * 512 + k];
}

// ---------------- one-time: W_hh into per-lane register layout -------------
__global__ __launch_bounds__(256) void k_wprep_hh(const float* __restrict__ wf,
                                                  const float* __restrict__ wb,
                                                  float* __restrict__ wt) {
    int o = blockIdx.x * 256 + threadIdx.x;   // 2*16*256*64
    int c    = o & 3;
    int i4   = (o >> 2) & 3;
    int q    = (o >> 4) & 3;
    int lane = (o >> 6) & 255;
    int jg   = (o >> 14) & 15;
    int d    = o >> 18;
    int jj = lane & 15, kseg = lane >> 4;
    const float* W = d ? wb : wf;
    wt[o] = W[(q * 256 + jg * 16 + jj) * 256 + kseg * 16 + i4 * 4 + c];
}

// ---------------- one-time full xg = uh0 @ W_ih^T (len=64) ----------------
__global__ __launch_bounds__(256) void k_xg(const float* __restrict__ units,
                                            const float* __restrict__ wihT,
                                            float* __restrict__ xg, int len, int offL) {
    __shared__ __align__(16) float As[32 * 132];
    __shared__ __align__(16) float Bs[32 * 132];
    int tid = threadIdx.x;
    int nt = blockIdx.x, mtb = blockIdx.y;
    int d = nt >> 3;
    int gbase = (nt & 7) * 128;
    int M = 128 * len;

    int arow = tid & 127, ahalf = tid >> 7;
    int agm = mtb * 128 + arow;
    const float* aptr = nullptr;
    if (agm < M) {
        int ab = agm / len, at = agm - ab * len;
        aptr = units + ((size_t)ab * TOTROWS + offL + at) * 512;
    }
    int bcol = (tid & 31) * 4, bkr = tid >> 5;
    int tm = tid >> 4, tn = tid & 15;

    float acc[8][8];
#pragma unroll
    for (int i = 0; i < 8; i++)
#pragma unroll
        for (int j = 0; j < 8; j++) acc[i][j] = 0.f;

    for (int k0 = 0; k0 < 512; k0 += 32) {
#pragma unroll
        for (int i4 = 0; i4 < 4; i4++) {
            float4 v;
            if (aptr) v = *(const float4*)&aptr[k0 + ahalf * 16 + i4 * 4];
            else { v.x = v.y = v.z = v.w = 0.f; }
            int kk = ahalf * 16 + i4 * 4;
            As[(kk + 0) * 132 + arow] = v.x;
            As[(kk + 1) * 132 + arow] = v.y;
            As[(kk + 2) * 132 + arow] = v.z;
            As[(kk + 3) * 132 + arow] = v.w;
        }
#pragma unroll
        for (int i = 0; i < 4; i++) {
            int kk = bkr * 4 + i;
            float4 v = *(const float4*)&wihT[((size_t)(d * 512 + k0 + kk)) * 1024 + gbase + bcol];
            *(float4*)&Bs[kk * 132 + bcol] = v;
        }
        __syncthreads();
#pragma unroll 4
        for (int k = 0; k < 32; k++) {
            float4 a0 = *(const float4*)&As[k * 132 + tm * 8];
            float4 a1 = *(const float4*)&As[k * 132 + tm * 8 + 4];
            float4 b0 = *(const float4*)&Bs[k * 132 + tn * 8];
            float4 b1 = *(const float4*)&Bs[k * 132 + tn * 8 + 4];
            float av[8] = {a0.x, a0.y, a0.z, a0.w, a1.x, a1.y, a1.z, a1.w};
            float bv[8] = {b0.x, b0.y, b0.z, b0.w, b1.x, b1.y, b1.z, b1.w};
#pragma unroll
            for (int i = 0; i < 8; i++)
#pragma unroll
                for (int j = 0; j < 8; j++) acc[i][j] = fmaf(av[i], bv[j], acc[i][j]);
        }
        __syncthreads();
    }
#pragma unroll
    for (int i = 0; i < 8; i++) {
        int gm = mtb * 128 + tm * 8 + i;
        if (gm < M) {
            int bb = gm / len, tt = gm - bb * len;
            float* Cp = xg + ((size_t)(d * B + bb) * L + tt) * G4 + gbase + tn * 8;
            float4 v0; v0.x = acc[i][0]; v0.y = acc[i][1]; v0.z = acc[i][2]; v0.w = acc[i][3];
            float4 v1; v1.x = acc[i][4]; v1.y = acc[i][5]; v1.z = acc[i][6]; v1.w = acc[i][7];
            *(float4*)&Cp[0] = v0;
            *(float4*)&Cp[4] = v1;
        }
    }
}

// ---------------- persistent: NaN-poison dataflow; no stage->dot sync ----
// block = (jg = bid&15, sg = (bid>>4)&7, d = bid>>7). Group = sg (32 blocks).
// stage thread (bS,kc) and dot thread (jj,kseg=kc) are the SAME 16 lanes ->
// hs region per kseg is quarter-wave-private, no barrier needed stage->dot.
// pb single-buffered: dot-write -> sync -> finalize-read -> sync -> next write.
__global__ __launch_bounds__(256, 1) void k_persist(
        float* __restrict__ xg, const float* __restrict__ wtHH,
        const float* __restrict__ bias_f, const float* __restrict__ bias_b,
        const float* __restrict__ ow, const float* __restrict__ h0,
        const float* __restrict__ c0, float* __restrict__ hst,
        double* __restrict__ o_part, const float* __restrict__ ob,
        const int* __restrict__ ex_in, float* __restrict__ dec,
        float* __restrict__ units, float* __restrict__ out_or,
        float* __restrict__ out_ex, int* flags) {
    __shared__ __align__(16) float hs[256 * 16];     // 16KB, kseg-region private
    __shared__ __align__(16) float pb[8 * 16 * 68];  // 34.8KB
    __shared__ float osh[68];
    __shared__ float dsh[64];
    __shared__ float exl[64];
    int tid = threadIdx.x;
    int bid = blockIdx.x;
    int jg = bid & 15, sg = (bid >> 4) & 7, d = bid >> 7;
    int lid = jg + 16 * d;
    int b0 = sg * 16, j0 = jg * 16;
    const size_t HB = (size_t)2 * B * H;             // per-step h stride

    int* gflag = flags + sg * 32 * GF_PAD;
    int* ggen  = flags + 4096 + sg * GF_PAD;
    int gph = 0;

    // W_hh slice resident in registers for the whole kernel
    float4 wreg[16];
    {
        const float4* wp = (const float4*)(wtHH + ((size_t)(d * 16 + jg) * 256 + tid) * 64);
#pragma unroll
        for (int m = 0; m < 16; m++) wreg[m] = wp[m];
    }
    int bF = tid >> 4, jjF = tid & 15;
    int bG = b0 + bF, jG = j0 + jjF;
    const float* biasp = d ? bias_b : bias_f;
    float bias4[4] = { biasp[jG], biasp[256 + jG], biasp[512 + jG], biasp[768 + jG] };
    float owv = ow[d * H + jG];
    float c0v = c0[d * H + jG];
    int bS = tid & 15, kc = tid >> 4;
    int swz = (((bS >> 2) ^ (kc & 3)) << 2) + (bS & 3);
    float4 h0s[4];
#pragma unroll
    for (int i4 = 0; i4 < 4; i4++)
        h0s[i4] = *(const float4*)&h0[d * H + kc * 16 + i4 * 4];
    const float* hstb = hst + ((size_t)(d * B + b0 + bS)) * H + kc * 16;
    float*       hwr  = hst + ((size_t)(d * B + bG)) * H + jG;
    float c_reg = 0.f;
    if (d == 0 && tid < 64) exl[tid] = (ex_in[(b0 + jg) * 64 + tid] != 0) ? 1.0f : 0.0f;

    for (int it = 0; it < 64; ++it) {
        int len = 64 - it;
        int offL = len * (len - 1) / 2;
        int n = len - 1;

        // ---- timestep chain (dataflow; blocking poll with backoff) ----
        for (int s = 0; s < len; ++s) {
            int t = d ? (n - s) : s;
            size_t xgo = (((size_t)(d * B + bG)) * L + t) * G4 + jG;
            float x0 = xg[xgo], x1 = xg[xgo + 256], x2 = xg[xgo + 512], x3 = xg[xgo + 768];
            if (s == 0) {
#pragma unroll
                for (int i4 = 0; i4 < 4; i4++) {
                    int kk = kc * 16 + i4 * 4;
                    hs[(kk + 0) * 16 + swz] = h0s[i4].x;
                    hs[(kk + 1) * 16 + swz] = h0s[i4].y;
                    hs[(kk + 2) * 16 + swz] = h0s[i4].z;
                    hs[(kk + 3) * 16 + swz] = h0s[i4].w;
                }
            } else {
                const float* hp = hstb + (size_t)(s - 1) * HB;
                fx4 v0, v1, v2, v3;
                ld4x4_sc(hp, v0, v1, v2, v3);
                while (any_nan(v0) | any_nan(v1) | any_nan(v2) | any_nan(v3)) {
                    __builtin_amdgcn_s_sleep(2);
                    ld4x4_sc(hp, v0, v1, v2, v3);
                }
                float arr[16] = { v0[0], v0[1], v0[2], v0[3], v1[0], v1[1], v1[2], v1[3],
                                  v2[0], v2[1], v2[2], v2[3], v3[0], v3[1], v3[2], v3[3] };
#pragma unroll
                for (int i = 0; i < 16; i++)
                    hs[(kc * 16 + i) * 16 + swz] = arr[i];
            }
            // NO __syncthreads here: stage->dot dependency is quarter-wave-private
            {   // dot
                int jj = tid & 15, kseg = tid >> 4;
                int ks3 = kseg & 3;
                float acc[4][16];
#pragma unroll
                for (int q = 0; q < 4; q++)
#pragma unroll
                    for (int u = 0; u < 16; u++) acc[q][u] = 0.f;
#pragma unroll
                for (int i4 = 0; i4 < 4; i4++) {
#pragma unroll
                    for (int c = 0; c < 4; c++) {
                        int k = (kseg << 4) + (i4 << 2) + c;
                        const float* hb = &hs[k << 4];
                        float4 hv[4];
#pragma unroll
                        for (int bq = 0; bq < 4; bq++)
                            hv[bq] = *(const float4*)&hb[((bq ^ ks3) << 2)];
#pragma unroll
                        for (int q = 0; q < 4; q++) {
                            float4 wv = wreg[q * 4 + i4];
                            float w = (c == 0) ? wv.x : (c == 1) ? wv.y : (c == 2) ? wv.z : wv.w;
#pragma unroll
                            for (int bq = 0; bq < 4; bq++) {
                                acc[q][bq * 4 + 0] = fmaf(hv[bq].x, w, acc[q][bq * 4 + 0]);
                                acc[q][bq * 4 + 1] = fmaf(hv[bq].y, w, acc[q][bq * 4 + 1]);
                                acc[q][bq * 4 + 2] = fmaf(hv[bq].z, w, acc[q][bq * 4 + 2]);
                                acc[q][bq * 4 + 3] = fmaf(hv[bq].w, w, acc[q][bq * 4 + 3]);
                            }
                        }
                    }
                }
#pragma unroll
                for (int q = 0; q < 4; q++)
#pragma unroll
                    for (int u = 0; u < 16; u++) acc[q][u] += __shfl_xor(acc[q][u], 32);
                if (!(tid & 32)) {
                    int slice = ((tid >> 6) << 1) | ((tid >> 4) & 1);
                    float* pbp = &pb[(slice * 16 + jj) * 68];
#pragma unroll
                    for (int bb = 0; bb < 16; bb++) {
                        float4 v; v.x = acc[0][bb]; v.y = acc[1][bb]; v.z = acc[2][bb]; v.w = acc[3][bb];
                        *(float4*)&pbp[bb * 4] = v;
                    }
                }
            }
            __syncthreads();
            {   // finalize
                float g4[4] = {0.f, 0.f, 0.f, 0.f};
#pragma unroll
                for (int sl = 0; sl < 8; sl++) {
                    float4 pv = *(const float4*)&pb[(sl * 16 + jjF) * 68 + bF * 4];
                    g4[0] += pv.x; g4[1] += pv.y; g4[2] += pv.z; g4[3] += pv.w;
                }
                float g0 = x0 + bias4[0] + g4[0];
                float g1 = x1 + bias4[1] + g4[1];
                float g2 = x2 + bias4[2] + g4[2];
                float g3 = x3 + bias4[3] + g4[3];
                float c_old = (s == 0) ? c0v : c_reg;
                float ig = sigf(g0);
                float fg = sigf(g1);
                float gv = tanhf(g2);
                float og = sigf(g3);
                float c = fg * c_old + ig * gv;
                float h = og * tanhf(c);
                c_reg = c;
                stg_sc_f32(hwr + (size_t)s * HB, h);
                double contrib = (double)h * (double)owv;
#pragma unroll
                for (int off = 8; off > 0; off >>= 1) contrib += __shfl_xor(contrib, off, 16);
                if (jjF == 0) stg_sc_f64(&o_part[(((size_t)(d * 16 + jg)) * B + bG) * L + t], contrib);
            }
            __syncthreads();
        }
        ++gph; group_barrier(gflag, ggen, lid, gph);

        // ---- orient + decisions (d==0 blocks; sample b0+jg each) ----
        if (d == 0) {
            int bo = b0 + jg;
            float oval = 0.f;
            if (tid < len) {
                double sum = (double)ob[0];
#pragma unroll 4
                for (int i = 0; i < 32; i++) sum += o_part[((size_t)i * B + bo) * L + tid];
                oval = (float)sum;
                osh[tid] = oval;
                out_or[(size_t)bo * TOTROWS + offL + tid] = oval;
                out_ex[(size_t)bo * TOTROWS + offL + tid] = exl[tid];
            }
            __syncthreads();
            float newex = 0.f;
            if (tid < n) {
                float lw = (oval > 0.f && exl[tid] != 0.f) ? 1.f : 0.f;
                float rw = (!(osh[tid + 1] > 0.f) && exl[tid + 1] != 0.f) ? 1.f : 0.f;
                stg_sc_f32(dec + bo * 64 + tid, lw + 2.f * rw);
                newex = ((lw + rw) > 0.f) ? 1.f : 0.f;
            }
            __syncthreads();
            if (tid < n) exl[tid] = newex;
        }
        ++gph; group_barrier(gflag, ggen, lid, gph);

        // ---- merge units + xg (group-local assignment) + re-arm h poison ----
        if (len > 1) {
            int bu = b0 + (lid >> 1);
            if (tid < n) dsh[tid] = dec[bu * 64 + tid];
            __syncthreads();
            {   // units: column (bu, k)
                int k = ((lid & 1) << 8) + tid;
                const float* src = units + ((size_t)bu * TOTROWS + offL) * D + k;
                float* dst = units + ((size_t)bu * TOTROWS + (offL - n)) * D + k;
                float cur = src[0];
                int tt = 0;
                while (tt < n) {
                    int m = (n - tt < 8) ? (n - tt) : 8;
                    float nx[8];
#pragma unroll
                    for (int i = 0; i < 8; i++) if (i < m) nx[i] = src[(size_t)(tt + i + 1) * D];
#pragma unroll
                    for (int i = 0; i < 8; i++) if (i < m) {
                        int dv = (int)dsh[tt + i];
                        stg_sc_f32(dst + (size_t)(tt + i) * D,
                                   (float)(dv & 1) * cur + (float)(dv >> 1) * nx[i]);
                        cur = nx[i];
                    }
                    tt += m;
                }
            }
            {   // xg: (d2 = lid&1, sample bu), float4 per thread
                int d2 = lid & 1;
                float* base = xg + ((size_t)(d2 * B + bu) * L) * G4 + tid * 4;
                float4 cur = *(const float4*)base;
                int tt = 0;
                while (tt < n) {
                    int m = (n - tt < 8) ? (n - tt) : 8;
                    float4 nx[8];
#pragma unroll
                    for (int i = 0; i < 8; i++) if (i < m)
                        nx[i] = *(const float4*)(base + (size_t)(tt + i + 1) * G4);
#pragma unroll
                    for (int i = 0; i < 8; i++) if (i < m) {
                        int dv = (int)dsh[tt + i];
                        float flw = (float)(dv & 1), frw = (float)(dv >> 1);
                        float4 o;
                        o.x = flw * cur.x + frw * nx[i].x;
                        o.y = flw * cur.y + frw * nx[i].y;
                        o.z = flw * cur.z + frw * nx[i].z;
                        o.w = flw * cur.w + frw * nx[i].w;
                        stg_sc_f4(base + (size_t)(tt + i) * G4, o);
                        cur = nx[i];
                    }
                    tt += m;
                }
            }
            {   // poison own (b,j) h-tile for next iteration
                float qn = __uint_as_float(0x7fc00000u);
                for (int s2 = 0; s2 < n; ++s2)
                    stg_sc_f32(hwr + (size_t)s2 * HB, qn);
            }
            ++gph; group_barrier(gflag, ggen, lid, gph);
        }
    }
}

extern "C" void kernel_launch(void* const* d_in, const int* in_sizes, int n_in,
                              void* d_out, int out_size, void* d_ws, size_t ws_size,
                              hipStream_t stream) {
    const int*   ex_in   = (const int*)d_in[0];
    const float* uh_in   = (const float*)d_in[1];
    const float* w_ih_f  = (const float*)d_in[2];
    const float* w_hh_f  = (const float*)d_in[3];
    const float* b_f     = (const float*)d_in[4];
    const float* w_ih_b  = (const float*)d_in[5];
    const float* w_hh_b  = (const float*)d_in[6];
    const float* b_b     = (const float*)d_in[7];
    const float* orientw = (const float*)d_in[8];
    const float* orientb = (const float*)d_in[9];
    const float* h0      = (const float*)d_in[10];
    const float* c0      = (const float*)d_in[11];

    float* units  = (float*)d_out;
    float* out_or = units + (size_t)B * TOTROWS * D;
    float* out_ex = out_or + (size_t)B * TOTROWS;

    float* xg    = (float*)d_ws;                       // 16,777,216 f (64MB)
    float* wihT  = xg + (size_t)2 * B * L * G4;        // 1,048,576 f
    float* wtHH  = wihT + (size_t)1048576;             // 524,288 f
    float* hst   = wtHH + (size_t)524288;              // 64 * 2*B*H = 4,194,304 f (16MB)
    float* dec   = hst + (size_t)64 * 2 * B * H;       // 8,192 f
    double* opart = (double*)(dec + B * L);            // 262,144 d (2MB)
    int*   flags = (int*)(opart + 262144);             // 8,448 ints

    k_init<<<4096, 256, 0, stream>>>(ex_in, uh_in, units, hst, flags);
    k_wprep_ih<<<4096, 256, 0, stream>>>(w_ih_f, w_ih_b, wihT);
    k_wprep_hh<<<2048, 256, 0, stream>>>(w_hh_f, w_hh_b, wtHH);
    k_xg<<<dim3(16, 64), 256, 0, stream>>>(units, wihT, xg, 64, 2016);
    k_persist<<<NBLK, 256, 0, stream>>>(xg, wtHH, b_f, b_b, orientw, h0, c0,
                                        hst, opart, orientb, ex_in, dec,
                                        units, out_or, out_ex, flags);
    (void)in_sizes; (void)n_in; (void)out_size; (void)ws_size;
}